// Round 3
// baseline (274.321 us; speedup 1.0000x reference)
//
#include <hip/hip_runtime.h>
#include <hip/hip_bf16.h>

#define B_ 16
#define C_ 256
#define N_ 4096
#define CN_ (C_ * N_)   // 1048576

typedef __attribute__((ext_vector_type(8))) short bf16x8_t;
typedef __attribute__((ext_vector_type(8))) unsigned short u16x8_t;
typedef __attribute__((ext_vector_type(4))) float f32x4_t;
typedef unsigned int u32;
typedef unsigned short u16;

__device__ __forceinline__ u16 f2bf(float f) {
    __hip_bfloat16 h = __float2bfloat16(f);
    return __builtin_bit_cast(u16, h);
}
__device__ __forceinline__ float bf2f(u16 u) {
    return __builtin_bit_cast(float, (u32)u << 16);
}

// async global->LDS, 16B per lane; lds base wave-uniform (HW adds lane*16)
__device__ __forceinline__ void gl_lds16(const void* g, void* l) {
    __builtin_amdgcn_global_load_lds(
        (const __attribute__((address_space(1))) u32*)(g),
        (__attribute__((address_space(3))) u32*)(l), 16, 0, 0);
}

// ---------------- kernel 1: norms + bf16 normalize + sums ----------------
// LDS-stage the rows so the compiler cannot rematerialize global loads.
__global__ __launch_bounds__(256) void knorm(const float* __restrict__ x1,
                                             const float* __restrict__ x2,
                                             u16* __restrict__ x1n,
                                             u16* __restrict__ x2n,
                                             u16* __restrict__ sN,
                                             u16* __restrict__ sxb,
                                             float* __restrict__ norms) {
    __shared__ float sx1[4096];
    __shared__ float sx2[4096];
    int row = blockIdx.x;              // b*256 + c
    int t = threadIdx.x;
    const float4* r1 = (const float4*)(x1 + (size_t)row * N_);
    const float4* r2 = (const float4*)(x2 + (size_t)row * N_);
    float s1 = 0.f, s2 = 0.f;
#pragma unroll
    for (int p = 0; p < 4; ++p) {
        float4 a = r1[p * 256 + t];
        float4 b = r2[p * 256 + t];
        s1 += a.x * a.x + a.y * a.y + a.z * a.z + a.w * a.w;
        s2 += b.x * b.x + b.y * b.y + b.z * b.z + b.w * b.w;
        *(float4*)&sx1[(p * 256 + t) * 4] = a;
        *(float4*)&sx2[(p * 256 + t) * 4] = b;
    }
#pragma unroll
    for (int m = 32; m; m >>= 1) { s1 += __shfl_xor(s1, m); s2 += __shfl_xor(s2, m); }
    __shared__ float red[2][4];
    int wid = t >> 6;
    if ((t & 63) == 0) { red[0][wid] = s1; red[1][wid] = s2; }
    __syncthreads();                                   // also makes sx1/sx2 visible
    s1 = red[0][0] + red[0][1] + red[0][2] + red[0][3];
    s2 = red[1][0] + red[1][1] + red[1][2] + red[1][3];
    float n1 = fmaxf(sqrtf(s1), 1e-12f);
    float n2 = fmaxf(sqrtf(s2), 1e-12f);
    if (t == 0) {
        int bb = row >> 8, cc = row & 255;
        norms[(bb * 2 + 0) * 256 + cc] = n1;
        norms[(bb * 2 + 1) * 256 + cc] = n2;
    }
    float i1 = 1.0f / n1, i2 = 1.0f / n2;
    const size_t rbase = (size_t)row * N_;
#pragma unroll
    for (int j = 0; j < 2; ++j) {
        int e = j * 2048 + t * 8;
        float a[8], b[8];
        *(float4*)&a[0] = *(const float4*)&sx1[e];
        *(float4*)&a[4] = *(const float4*)&sx1[e + 4];
        *(float4*)&b[0] = *(const float4*)&sx2[e];
        *(float4*)&b[4] = *(const float4*)&sx2[e + 4];
        u16x8_t w1, w2, ws, wr;
#pragma unroll
        for (int i = 0; i < 8; ++i) {
            float va = a[i] * i1, vb = b[i] * i2;
            w1[i] = f2bf(va);
            w2[i] = f2bf(vb);
            ws[i] = f2bf(va + vb);
            wr[i] = f2bf(a[i] + b[i]);
        }
        *(u16x8_t*)(x1n + rbase + e) = w1;
        *(u16x8_t*)(x2n + rbase + e) = w2;
        *(u16x8_t*)(sN  + rbase + e) = ws;
        *(u16x8_t*)(sxb + rbase + e) = wr;
    }
}

// ------ kernel 2: part[kc] = sN @ x{w}n^T over K-chunk (both w fused) -----
// 64c x 64d tile, K-split x4 (1024 each, 16 steps of BK=64), dbuf LDS.
__global__ __launch_bounds__(256) void klogits(const u16* __restrict__ sN,
                                               const u16* __restrict__ x1n,
                                               const u16* __restrict__ x2n,
                                               float* __restrict__ part) {
    int bid = blockIdx.x;                 // 1024 blocks
    int xcd = bid & 7;
    int u = bid >> 3;                     // 0..127
    int b = xcd + 8 * (u & 1);
    int tile = (u >> 1) & 15;
    int kc4 = u >> 5;                     // 0..3 K-chunk
    int c0 = (tile & 3) * 64;
    int d0 = (tile >> 2) * 64;

    __shared__ u16 lds[2][3 * 4096];      // 2 x 24KB

    int t = threadIdx.x, lane = t & 63, wid = t >> 6;
    int w = wid & 1, chalf = wid >> 1;

    const char* tb[3];
    tb[0] = (const char*)(sN  + (size_t)b * CN_ + (size_t)c0 * N_ + kc4 * 1024);
    tb[1] = (const char*)(x1n + (size_t)b * CN_ + (size_t)d0 * N_ + kc4 * 1024);
    tb[2] = (const char*)(x2n + (size_t)b * CN_ + (size_t)d0 * N_ + kc4 * 1024);
    const char* gsrc[6];
    int ldoff[6];
#pragma unroll
    for (int qq = 0; qq < 6; ++qq) {
        int q = wid * 6 + qq;             // 24 chunks of 1KB
        int ti = q >> 3;
        int s0 = (q & 7) * 1024 + lane * 16;
        int rrow = s0 >> 7, inner = s0 & 127;
        gsrc[qq] = tb[ti] + (size_t)rrow * (N_ * 2) + (inner ^ ((rrow & 7) << 4));
        ldoff[qq] = q * 1024;
    }

    f32x4_t acc[2][4];
#pragma unroll
    for (int i = 0; i < 2; ++i)
#pragma unroll
        for (int j = 0; j < 4; ++j) acc[i][j] = 0.f;

    int kl = (lane >> 4) * 16;            // byte offset within 128B row
    int rA0 = chalf * 32 + (lane & 15);

    // prologue: stage step 0 into buf 0
#pragma unroll
    for (int qq = 0; qq < 6; ++qq)
        gl_lds16(gsrc[qq], (char*)lds[0] + ldoff[qq]);
    __syncthreads();

    for (int ks = 0; ks < 16; ++ks) {
        int p = ks & 1;
        if (ks < 15) {
            int kbyte = (ks + 1) * 128;
#pragma unroll
            for (int qq = 0; qq < 6; ++qq)
                gl_lds16(gsrc[qq] + kbyte, (char*)lds[p ^ 1] + ldoff[qq]);
        }
        const char* Abase = (const char*)lds[p];
        const char* Bbase = (const char*)lds[p] + (1 + w) * 8192;
#pragma unroll
        for (int ksub = 0; ksub < 2; ++ksub) {
            int kc = ksub * 64 + kl;
            bf16x8_t af[2], bfr[4];
#pragma unroll
            for (int mi = 0; mi < 2; ++mi) {
                int rr = rA0 + mi * 16;
                af[mi] = *(const bf16x8_t*)(Abase + ((rr << 7) + (kc ^ ((rr & 7) << 4))));
            }
#pragma unroll
            for (int ni = 0; ni < 4; ++ni) {
                int rr = ni * 16 + (lane & 15);
                bfr[ni] = *(const bf16x8_t*)(Bbase + ((rr << 7) + (kc ^ ((rr & 7) << 4))));
            }
#pragma unroll
            for (int mi = 0; mi < 2; ++mi)
#pragma unroll
                for (int ni = 0; ni < 4; ++ni)
                    acc[mi][ni] = __builtin_amdgcn_mfma_f32_16x16x32_bf16(af[mi], bfr[ni], acc[mi][ni], 0, 0, 0);
        }
        __syncthreads();   // drains next-step stage (it had the MFMA phase to land)
    }

    float* outp = part + ((((size_t)kc4 * 16 + b) * 2 + w) * 256 + c0 + chalf * 32) * 256 + d0;
    int orow = (lane >> 4) * 4, ocol = lane & 15;
#pragma unroll
    for (int mi = 0; mi < 2; ++mi)
#pragma unroll
        for (int ni = 0; ni < 4; ++ni)
#pragma unroll
            for (int r = 0; r < 4; ++r)
                outp[(size_t)(mi * 16 + orow + r) * 256 + ni * 16 + ocol] = acc[mi][ni][r];
}

// ---- kernel 3: sum 4 K-partials, row softmax, fold norm[d], emit bf16 ----
__global__ __launch_bounds__(256) void ksoftmax(const float* __restrict__ part,
                                                const float* __restrict__ norms,
                                                u16* __restrict__ attnp) {
    const size_t S = 2097152;            // elems per K-chunk partial
    int rid = blockIdx.x * 4 + (threadIdx.x >> 6);   // (b*2+w)*256 + c
    int l = threadIdx.x & 63;
    int bw = rid >> 8, c = rid & 255;
    size_t rbase = (size_t)bw * 65536 + (size_t)c * 256;
    float v[4];
    float m = -1e30f;
#pragma unroll
    for (int j = 0; j < 4; ++j) {
        int d = j * 64 + l;
        v[j] = part[rbase + d] + part[rbase + S + d] +
               part[rbase + 2 * S + d] + part[rbase + 3 * S + d];
        m = fmaxf(m, v[j]);
    }
#pragma unroll
    for (int s = 32; s; s >>= 1) m = fmaxf(m, __shfl_xor(m, s));
    float sum = 0.f;
#pragma unroll
    for (int j = 0; j < 4; ++j) { v[j] = __expf(v[j] - m); sum += v[j]; }
#pragma unroll
    for (int s = 32; s; s >>= 1) sum += __shfl_xor(sum, s);
    float rs = 1.0f / sum;
    u16* outp = attnp + (size_t)rid * 256;
    const float* nr = norms + (size_t)bw * 256;
#pragma unroll
    for (int j = 0; j < 4; ++j)
        outp[j * 64 + l] = f2bf(v[j] * rs * nr[j * 64 + l]);
}

// ------- kernel 4: out[n,c] = yT1 + yT2 + (x1+x2) (fused both which) ------
// A (64n x 64d) reg-transposed into dbuf LDS (T14 pipelined);
// B fragments loaded directly from global (attn is L2-resident).
__global__ __launch_bounds__(256) void kout(const u16* __restrict__ x1n,
                                            const u16* __restrict__ x2n,
                                            const u16* __restrict__ attnp,
                                            const u16* __restrict__ sxb,
                                            float* __restrict__ out) {
    int bid = blockIdx.x;              // 2048 blocks
    int xcd = bid & 7;
    int u = bid >> 3;                  // 0..255
    int b = xcd + 8 * (u & 1);
    int rest = u >> 1;                 // 0..127
    int n0 = (rest >> 1) * 64;
    int c0 = (rest & 1) * 128;

    __shared__ u16 sA[2][2][4096];     // [buf][tensor][64n x 64d] swizzled, 32KB

    int t = threadIdx.x, lane = t & 63, wid = t >> 6;
    int wc = wid;                      // 32-wide c slice per wave

    int tensorA = t >> 7;              // staging: 2 waves per tensor
    int tt = t & 127;
    int dq = (tt & 15) * 4;            // 4 consecutive d rows
    int n8 = (tt >> 4) * 8;            // 8 consecutive n cols
    const u16* Asrc = (tensorA ? x2n : x1n) + (size_t)b * CN_ + n0 + n8;

    // B fragment row bases: [tensor][ci]
    const char* Bb[2][2];
#pragma unroll
    for (int tensor = 0; tensor < 2; ++tensor)
#pragma unroll
        for (int ci = 0; ci < 2; ++ci)
            Bb[tensor][ci] = (const char*)(attnp +
                ((size_t)(b * 2 + tensor) * 256 + c0 + wc * 32 + ci * 16 + (lane & 15)) * 256);

    f32x4_t acc1[4][2], acc2[4][2];
#pragma unroll
    for (int i = 0; i < 4; ++i)
#pragma unroll
        for (int j = 0; j < 2; ++j) { acc1[i][j] = 0.f; acc2[i][j] = 0.f; }

    int kl = (lane >> 4) * 16;

    uint4 r0, r1, r2, r3;
#define LOADA(KS) do { \
        size_t kk = (size_t)((KS) * 64 + dq); \
        r0 = *(const uint4*)(Asrc + (kk + 0) * N_); \
        r1 = *(const uint4*)(Asrc + (kk + 1) * N_); \
        r2 = *(const uint4*)(Asrc + (kk + 2) * N_); \
        r3 = *(const uint4*)(Asrc + (kk + 3) * N_); \
    } while (0)
#define WRITEA(BUF) do { \
        const u16* p0 = (const u16*)&r0; \
        const u16* p1 = (const u16*)&r1; \
        const u16* p2 = (const u16*)&r2; \
        const u16* p3 = (const u16*)&r3; \
        char* dst = (char*)&sA[BUF][tensorA][0]; \
        _Pragma("unroll") \
        for (int i = 0; i < 8; ++i) { \
            u32 lo = (u32)p0[i] | ((u32)p1[i] << 16); \
            u32 hi = (u32)p2[i] | ((u32)p3[i] << 16); \
            int n = n8 + i; \
            int addr = (n << 7) + ((dq << 1) ^ ((n & 7) << 4)); \
            uint2 val; val.x = lo; val.y = hi; \
            *(uint2*)(dst + addr) = val; \
        } \
    } while (0)

    LOADA(0);
    WRITEA(0);

    for (int ks = 0; ks < 4; ++ks) {
        int p = ks & 1;
        __syncthreads();               // sA[p] visible
        if (ks < 3) LOADA(ks + 1);     // in flight during compute
        const char* A0 = (const char*)&sA[p][0][0];
        const char* A1 = (const char*)&sA[p][1][0];
#pragma unroll
        for (int ksub = 0; ksub < 2; ++ksub) {
            int kc = ksub * 64 + kl;
            int kb = ks * 128 + kc;    // byte offset within 512B attn row
            bf16x8_t a1f[4], a2f[4], b1f[2], b2f[2];
#pragma unroll
            for (int mi = 0; mi < 4; ++mi) {
                int rr = mi * 16 + (lane & 15);
                int ao = (rr << 7) + (kc ^ ((rr & 7) << 4));
                a1f[mi] = *(const bf16x8_t*)(A0 + ao);
                a2f[mi] = *(const bf16x8_t*)(A1 + ao);
            }
#pragma unroll
            for (int ci = 0; ci < 2; ++ci) {
                b1f[ci] = *(const bf16x8_t*)(Bb[0][ci] + kb);
                b2f[ci] = *(const bf16x8_t*)(Bb[1][ci] + kb);
            }
#pragma unroll
            for (int mi = 0; mi < 4; ++mi)
#pragma unroll
                for (int ci = 0; ci < 2; ++ci) {
                    acc1[mi][ci] = __builtin_amdgcn_mfma_f32_16x16x32_bf16(a1f[mi], b1f[ci], acc1[mi][ci], 0, 0, 0);
                    acc2[mi][ci] = __builtin_amdgcn_mfma_f32_16x16x32_bf16(a2f[mi], b2f[ci], acc2[mi][ci], 0, 0, 0);
                }
        }
        if (ks < 3) WRITEA(p ^ 1);     // waits LOADA via data dep, after compute
    }

    const size_t obase = (size_t)b * CN_;
    int orow = (lane >> 4) * 4, ocol = lane & 15;
#pragma unroll
    for (int mi = 0; mi < 4; ++mi)
#pragma unroll
        for (int ci = 0; ci < 2; ++ci)
#pragma unroll
            for (int r = 0; r < 4; ++r) {
                int n = n0 + mi * 16 + orow + r;
                int c = c0 + wc * 32 + ci * 16 + ocol;
                size_t f = obase + (size_t)n * 256 + c;
                out[f] = acc1[mi][ci][r] + acc2[mi][ci][r] + bf2f(sxb[f]);
            }
#undef LOADA
#undef WRITEA
}

// --------------------------------- launch ---------------------------------
extern "C" void kernel_launch(void* const* d_in, const int* in_sizes, int n_in,
                              void* d_out, int out_size, void* d_ws, size_t ws_size,
                              hipStream_t stream) {
    const float* x1 = (const float*)d_in[0];
    const float* x2 = (const float*)d_in[1];
    float* out = (float*)d_out;

    char* ws = (char*)d_ws;
    u16*   x1n   = (u16*)(ws);                         // 32 MB
    u16*   x2n   = (u16*)(ws + 33554432ull);           // 32 MB
    u16*   sN    = (u16*)(ws + 67108864ull);           // 32 MB
    u16*   sxb   = (u16*)(ws + 100663296ull);          // 32 MB
    float* part  = (float*)(ws + 134217728ull);        // 32 MB (4 x 8MB K-partials)
    u16*   attnp = (u16*)(ws + 167772160ull);          //  4 MB
    float* norms = (float*)(ws + 171966464ull);        // 32 KB

    knorm<<<4096, 256, 0, stream>>>(x1, x2, x1n, x2n, sN, sxb, norms);
    klogits<<<1024, 256, 0, stream>>>(sN, x1n, x2n, part);
    ksoftmax<<<2048, 256, 0, stream>>>(part, norms, attnp);
    kout<<<2048, 256, 0, stream>>>(x1n, x2n, attnp, sxb, out);
}